// Round 21
// baseline (295.073 us; speedup 1.0000x reference)
//
#include <hip/hip_runtime.h>
#include <hip/hip_fp8.h>
#include <stdint.h>

typedef __attribute__((ext_vector_type(8))) short bf16x8;
typedef __attribute__((ext_vector_type(4))) float f32x4;
typedef __attribute__((ext_vector_type(16))) float f32x16;
typedef __attribute__((ext_vector_type(4))) unsigned short u16x4;

static constexpr int Bn = 4, Sn = 2048, Dn = 1024, Hn = 16, HD = 64;
static constexpr int Mrows = Bn * Sn;   // 8192
static constexpr int D3 = 3 * Dn;       // 3072

__device__ __forceinline__ unsigned short f2bf(float f) {
  unsigned int u = __float_as_uint(f);
  u += 0x7FFF + ((u >> 16) & 1);
  return (unsigned short)(u >> 16);
}

__device__ __forceinline__ unsigned char f2fp8(float f) {
  __hip_fp8_e4m3 v(f);
  return (unsigned char)v.__x;
}

__device__ __forceinline__ void gload16(const void* gptr, void* lptr) {
  __builtin_amdgcn_global_load_lds(
      (__attribute__((address_space(1))) void*)gptr,
      (__attribute__((address_space(3))) void*)lptr, 16, 0, 0);
}

__device__ __forceinline__ int swz8(int r) { return (r ^ (r >> 3)) & 7; }

__device__ __forceinline__ float vexp2(float x) {
#if __has_builtin(__builtin_amdgcn_exp2f)
  return __builtin_amdgcn_exp2f(x);
#else
  return exp2f(x);
#endif
}

__device__ __forceinline__ unsigned cvtpk(float lo, float hi) {
  unsigned r;
  asm("v_cvt_pk_bf16_f32 %0, %1, %2" : "=v"(r) : "v"(lo), "v"(hi));
  return r;
}

__device__ __forceinline__ float lanepull(float v, int srclane) {
  return __int_as_float(__builtin_amdgcn_ds_bpermute(srclane * 4, __float_as_int(v)));
}

// ---------------- elementwise f32 -> fp8 e4m3 ----------------
__global__ void cvt_f32_fp8(const float* __restrict__ in,
                            unsigned char* __restrict__ out, int n) {
  int i = (blockIdx.x * blockDim.x + threadIdx.x) * 4;
  if (i < n) {
    const float4 v = *(const float4*)(in + i);
    uchar4 o;
    o.x = f2fp8(v.x); o.y = f2fp8(v.y); o.z = f2fp8(v.z); o.w = f2fp8(v.w);
    *(uchar4*)(out + i) = o;
  }
}

// ---------------- W [K][N] f32 -> W^T [N][K] fp8 (scaled x64) ----------------
__global__ void transpose_cvt_fp8(const float* __restrict__ W,
                                  unsigned char* __restrict__ Wt, int K, int N) {
  __shared__ float tile[32][33];
  const int n0 = blockIdx.x * 32, k0 = blockIdx.y * 32;
  const int tx = threadIdx.x, ty = threadIdx.y;   // block (32,8)
  #pragma unroll
  for (int j = 0; j < 4; j++)
    tile[ty + 8 * j][tx] = W[(size_t)(k0 + ty + 8 * j) * N + n0 + tx];
  __syncthreads();
  #pragma unroll
  for (int j = 0; j < 4; j++)
    Wt[(size_t)(n0 + ty + 8 * j) * K + k0 + tx] = f2fp8(tile[tx][ty + 8 * j] * 64.0f);
}

// ---------------- 128x256 fp8 GEMM, BK=128 (round-19/20 proven) ----------------
template<bool BF16_OUT>
__global__ __launch_bounds__(512, 1)
void gemm_fp8(const unsigned char* __restrict__ A,
              const unsigned char* __restrict__ Bt,
              const float* __restrict__ bias,
              void* __restrict__ Cout, int Nt, int Kt) {
  __shared__ __align__(128) unsigned char smem[98304];  // 2 x (A 16K + B 32K)
  const int tid = threadIdx.x;
  const int w = tid >> 6, lane = tid & 63;
  const int wm = w >> 2, wn = w & 3;
  const int lrow = lane & 15, lk = lane >> 4;
  const long brow = (long)blockIdx.x * 128;
  const long bcol = (long)blockIdx.y * 256;

  const int srow = tid >> 3;    // 0..63
  const int sslot = tid & 7;

  auto stage = [&](int k0, unsigned char* buf) {   // 6 gloads: 2 A + 4 B
    unsigned char* Ab = buf;
    unsigned char* Bb = buf + 16384;
    #pragma unroll
    for (int i = 0; i < 2; i++) {
      const int r = srow + 64 * i;
      gload16(A + (size_t)(brow + r) * Kt + k0 + ((sslot ^ swz8(r)) * 16),
              Ab + w * 1024 + i * 8192);
    }
    #pragma unroll
    for (int i = 0; i < 4; i++) {
      const int r = srow + 64 * i;
      gload16(Bt + (size_t)(bcol + r) * Kt + k0 + ((sslot ^ swz8(r)) * 16),
              Bb + w * 1024 + i * 8192);
    }
  };

  f32x4 acc[4][4] = {};

  stage(0, smem);

  const int ntile = Kt >> 7;          // BK = 128
  for (int t = 0; t < ntile; t++) {
    const int cur = t & 1;
    unsigned char* Ab = smem + cur * 49152;
    unsigned char* Bb = Ab + 16384;

    __builtin_amdgcn_s_barrier();     // retires t-1 readers of buf^1
    if (t + 1 < ntile) {
      stage((t + 1) << 7, smem + (cur ^ 1) * 49152);
      asm volatile("s_waitcnt vmcnt(6)");  // t's 6 loads done; t+1's in flight
    } else {
      asm volatile("s_waitcnt vmcnt(0)");
    }
    __builtin_amdgcn_sched_barrier(0);
    __builtin_amdgcn_s_barrier();     // buf t visible block-wide

    const int sub = (lk & 1) * 8;
    #pragma unroll
    for (int kk = 0; kk < 4; kk++) {
      const int s16 = kk * 2 + (lk >> 1);
      long av[4], bv[4];
      #pragma unroll
      for (int mt = 0; mt < 4; mt++) {
        const int r = wm * 64 + mt * 16 + lrow;
        av[mt] = *(const long*)(Ab + r * 128 + (((s16 ^ swz8(r)) << 4) + sub));
      }
      #pragma unroll
      for (int nt = 0; nt < 4; nt++) {
        const int r = wn * 64 + nt * 16 + lrow;
        bv[nt] = *(const long*)(Bb + r * 128 + (((s16 ^ swz8(r)) << 4) + sub));
      }
      __builtin_amdgcn_s_setprio(1);
      #pragma unroll
      for (int mt = 0; mt < 4; mt++)
        #pragma unroll
        for (int nt = 0; nt < 4; nt++)
          acc[mt][nt] = __builtin_amdgcn_mfma_f32_16x16x32_fp8_fp8(av[mt], bv[nt], acc[mt][nt], 0, 0, 0);
      __builtin_amdgcn_s_setprio(0);
    }
  }

  #pragma unroll
  for (int nt = 0; nt < 4; nt++) {
    const long col = bcol + wn * 64 + nt * 16 + lrow;
    const float bv2 = bias[col];
    #pragma unroll
    for (int mt = 0; mt < 4; mt++) {
      #pragma unroll
      for (int rr = 0; rr < 4; rr++) {
        const long row = brow + wm * 64 + mt * 16 + lk * 4 + rr;
        const float v = acc[mt][nt][rr] * 0.015625f + bv2;
        if (BF16_OUT)
          ((unsigned short*)Cout)[row * Nt + col] = f2bf(v);
        else
          ((float*)Cout)[row * Nt + col] = v;
      }
    }
  }
}

// ---------------- flash attention: LPT 4-wave blocks, 16 waves/CU ----------------
// Block = (bh, y): m = 15-y (LPT: heaviest first), owns 128 q-rows
// [128m, 128m+128); wave w -> 32-row subtile. 1024 blocks, 4/CU co-resident
// (32 KB single-buffered LDS, launch_bounds(256,4) -> VGPR cap 128,
// 16 waves/CU = 4/SIMD: doubles SIMD-level latency hiding vs r18's 2).
// KV tile = 128 rows, SINGLE-buffered, 2 barriers/tile; K via gload_lds
// (pre-swizzled source), VT reg-staged scatter (r18-verbatim formulas).
// Epilogue emits fp8 e4m3 (feeds fp8 proj GEMM).
__global__ __launch_bounds__(256, 4)
void attn_lpt(const unsigned short* __restrict__ QKV,
              unsigned char* __restrict__ Out) {
  __shared__ __align__(128) unsigned char smem[32768]; // 16K K + 16K VT
  const int tid  = threadIdx.x;
  const int w    = tid >> 6;
  const int lane = tid & 63;
  const int li = lane & 31, hi = lane >> 5;
  const int bh = blockIdx.x;
  const int b  = bh >> 4, h = bh & 15;
  const int m  = 15 - (int)blockIdx.y;       // LPT: longest blocks dispatch first
  const int wq = m * 128 + w * 32;
  const int qrow = wq + li;

  const float cexp = 0.18033688011112042f;   // (1/8) * log2(e)

  bf16x8 qf[4];
  {
    const unsigned short* qp = QKV + (size_t)(b * Sn + qrow) * D3 + h * HD + hi * 8;
    #pragma unroll
    for (int ks = 0; ks < 4; ks++) qf[ks] = *(const bf16x8*)(qp + ks * 16);
  }

  f32x16 o0 = {}, o1 = {};
  float mm = -3.0e38f, ls = 0.f;

  unsigned char* Kb = smem;
  unsigned char* Vb = smem + 16384;

  // K stage: 4 gload rounds; round i covers rows [32i, 32i+32)
  auto kstage = [&](int kb) {
    #pragma unroll
    for (int i = 0; i < 4; i++) {
      const int r    = i * 32 + w * 8 + (lane >> 3);
      const int slot = (lane & 7) ^ swz8(r);
      gload16(QKV + (size_t)(b * Sn + kb + r) * D3 + Dn + h * HD + slot * 8,
              Kb + i * 4096 + w * 1024);
    }
  };
  const int vkv = tid >> 1;           // 0..127
  const int vd0 = (tid & 1) * 32;
  auto vload = [&](int kb, int jj) -> bf16x8 {
    return *(const bf16x8*)(QKV + (size_t)(b * Sn + kb + vkv) * D3 + 2 * Dn + h * HD + vd0 + jj * 8);
  };
  auto vwrite = [&](bf16x8 vv, int jj) {
    #pragma unroll
    for (int e = 0; e < 8; e++) {
      const int d  = vd0 + jj * 8 + e;
      const int vs = (d ^ (d >> 3)) & 15;
      *(unsigned short*)(Vb + d * 256 + (((vkv >> 3) ^ vs) << 4) + (vkv & 7) * 2) = (unsigned short)vv[e];
    }
  };

  // one 64-kv online-softmax sub-step (r18-verbatim)
  auto substep = [&](int s, int kb) {
    f32x16 s0 = {}, s1 = {};
    const int r0 = s * 64 + li, r1 = s * 64 + 32 + li;
    __builtin_amdgcn_s_setprio(1);
    #pragma unroll
    for (int ks = 0; ks < 4; ks++) {
      const int slot = ks * 2 + hi;
      const bf16x8 k0 = *(const bf16x8*)(Kb + r0 * 128 + ((slot ^ swz8(r0)) * 16));
      const bf16x8 k1 = *(const bf16x8*)(Kb + r1 * 128 + ((slot ^ swz8(r1)) * 16));
      s0 = __builtin_amdgcn_mfma_f32_32x32x16_bf16(k0, qf[ks], s0, 0, 0, 0);
      s1 = __builtin_amdgcn_mfma_f32_32x32x16_bf16(k1, qf[ks], s1, 0, 0, 0);
    }
    __builtin_amdgcn_s_setprio(0);
    const int kbase = kb + s * 64;
    if (kbase + 63 > wq) {   // diagonal: mask
      #pragma unroll
      for (int r = 0; r < 16; r++) {
        const int kvl = (r & 3) + 8 * (r >> 2) + 4 * hi;
        if (kbase + kvl > qrow)      s0[r] = -3.0e38f;
        if (kbase + 32 + kvl > qrow) s1[r] = -3.0e38f;
      }
    }
    float t8[8];
    #pragma unroll
    for (int r = 0; r < 8; r++)
      t8[r] = fmaxf(fmaxf(s0[r], s0[r + 8]), fmaxf(s1[r], s1[r + 8]));
    float tmax = fmaxf(fmaxf(fmaxf(t8[0], t8[1]), fmaxf(t8[2], t8[3])),
                       fmaxf(fmaxf(t8[4], t8[5]), fmaxf(t8[6], t8[7])));
    tmax = fmaxf(tmax, __shfl_xor(tmax, 32));
    if (__any(tmax > mm + 44.0f)) {   // defer-max
      const float mn   = fmaxf(mm, tmax);
      const float corr = vexp2((mm - mn) * cexp);
      mm = mn;
      ls *= corr;
      #pragma unroll
      for (int r = 0; r < 16; r++) {
        const float cr = lanepull(corr, (r & 3) + 8 * (r >> 2) + 4 * hi);
        o0[r] *= cr; o1[r] *= cr;
      }
    }
    const float mc = mm * cexp;
    f32x16 p0, p1;
    float psa = 0.f, psb = 0.f, psc = 0.f, psd = 0.f;
    #pragma unroll
    for (int r = 0; r < 16; r += 4) {
      p0[r] = vexp2(fmaf(s0[r], cexp, -mc));         psa += p0[r];
      p0[r + 1] = vexp2(fmaf(s0[r + 1], cexp, -mc)); psb += p0[r + 1];
      p0[r + 2] = vexp2(fmaf(s0[r + 2], cexp, -mc)); psc += p0[r + 2];
      p0[r + 3] = vexp2(fmaf(s0[r + 3], cexp, -mc)); psd += p0[r + 3];
    }
    #pragma unroll
    for (int r = 0; r < 16; r += 4) {
      p1[r] = vexp2(fmaf(s1[r], cexp, -mc));         psa += p1[r];
      p1[r + 1] = vexp2(fmaf(s1[r + 1], cexp, -mc)); psb += p1[r + 1];
      p1[r + 2] = vexp2(fmaf(s1[r + 2], cexp, -mc)); psc += p1[r + 2];
      p1[r + 3] = vexp2(fmaf(s1[r + 3], cexp, -mc)); psd += p1[r + 3];
    }
    ls += (psa + psb) + (psc + psd);

    auto mk_pa = [&](const f32x16& pp, int base) -> bf16x8 {
      const unsigned a0 = cvtpk(pp[base + 0], pp[base + 1]);
      const unsigned a1 = cvtpk(pp[base + 2], pp[base + 3]);
      const unsigned b0 = cvtpk(pp[base + 4], pp[base + 5]);
      const unsigned b1 = cvtpk(pp[base + 6], pp[base + 7]);
      const unsigned xa0 = __shfl_xor(a0, 32), xa1 = __shfl_xor(a1, 32);
      const unsigned xb0 = __shfl_xor(b0, 32), xb1 = __shfl_xor(b1, 32);
      union { unsigned u[4]; bf16x8 v; } pu;
      pu.u[0] = hi ? xb0 : a0;
      pu.u[1] = hi ? xb1 : a1;
      pu.u[2] = hi ? b0  : xa0;
      pu.u[3] = hi ? b1  : xa1;
      return pu.v;
    };
    bf16x8 pa[4];
    pa[0] = mk_pa(p0, 0); pa[1] = mk_pa(p0, 8);
    pa[2] = mk_pa(p1, 0); pa[3] = mk_pa(p1, 8);

    const int vs0 = (li ^ (li >> 3)) & 15;
    const int vs1 = ((32 + li) ^ ((32 + li) >> 3)) & 15;
    __builtin_amdgcn_s_setprio(1);
    #pragma unroll
    for (int k16 = 0; k16 < 4; k16++) {
      const int slot = s * 8 + k16 * 2 + hi;
      const bf16x8 vb0 = *(const bf16x8*)(Vb + li * 256 + ((slot ^ vs0) << 4));
      const bf16x8 vb1 = *(const bf16x8*)(Vb + (32 + li) * 256 + ((slot ^ vs1) << 4));
      o0 = __builtin_amdgcn_mfma_f32_32x32x16_bf16(pa[k16], vb0, o0, 0, 0, 0);
      o1 = __builtin_amdgcn_mfma_f32_32x32x16_bf16(pa[k16], vb1, o1, 0, 0, 0);
    }
    __builtin_amdgcn_s_setprio(0);
  };

  for (int t = 0; t <= m; t++) {
    const int kb = t << 7;
    __builtin_amdgcn_s_barrier();     // all waves done reading previous tile
    kstage(kb);                        // K -> LDS (async)
    {
      bf16x8 v0 = vload(kb, 0), v1 = vload(kb, 1), v2 = vload(kb, 2), v3 = vload(kb, 3);
      vwrite(v0, 0); vwrite(v1, 1); vwrite(v2, 2); vwrite(v3, 3);  // reg deps drain V
    }
    asm volatile("s_waitcnt vmcnt(0) lgkmcnt(0)");  // K LDS-writes + V ds_writes done
    __builtin_amdgcn_sched_barrier(0);
    __builtin_amdgcn_s_barrier();     // tile visible block-wide

    substep(0, kb);
    if (kb + 64 <= wq + 31) substep(1, kb);
  }

  // ---- epilogue: O / l -> fp8 e4m3 ----
  const float lt = ls + __shfl_xor(ls, 32);
  const float rl = __builtin_amdgcn_rcpf(lt);
  #pragma unroll
  for (int r = 0; r < 16; r++) {
    const int q = (r & 3) + 8 * (r >> 2) + 4 * hi;
    const float rr = lanepull(rl, q);
    unsigned char* op = Out + (size_t)(b * Sn + wq + q) * Dn + h * HD;
    op[li]      = f2fp8(o0[r] * rr);
    op[32 + li] = f2fp8(o1[r] * rr);
  }
}

// ---------------- tail: string_len -> float ----------------
__global__ void copy_len(const int* __restrict__ slen, float* __restrict__ dst, int n) {
  const int i = threadIdx.x;
  if (i < n) dst[i] = (float)slen[i];
}

extern "C" void kernel_launch(void* const* d_in, const int* in_sizes, int n_in,
                              void* d_out, int out_size, void* d_ws, size_t ws_size,
                              hipStream_t stream) {
  const float* X    = (const float*)d_in[0];
  const int*   slen = (const int*)d_in[1];
  const float* Wqkv = (const float*)d_in[2];
  const float* bqkv = (const float*)d_in[3];
  const float* Wo   = (const float*)d_in[4];
  const float* bo   = (const float*)d_in[5];
  float* out = (float*)d_out;

  char* ws = (char*)d_ws;
  unsigned char*  Xf8   = (unsigned char*)ws;                        // 8.4 MB (region 16 MB)
  unsigned char*  Wtq8  = (unsigned char*)(ws + 16777216);           // 3.1 MB (region 6 MB)
  unsigned char*  Wto8  = (unsigned char*)(ws + 16777216 + 6291456); // 1.05 MB (region 2 MB)
  unsigned short* QKVb  = (unsigned short*)(ws + 16777216 + 6291456 + 2097152);
  unsigned char*  Attnb = (unsigned char*)ws;   // X dead after QKV GEMM; reuse (fp8)

  cvt_f32_fp8<<<dim3(8192), dim3(256), 0, stream>>>(X, Xf8, Mrows * Dn);
  transpose_cvt_fp8<<<dim3(96, 32), dim3(32, 8), 0, stream>>>(Wqkv, Wtq8, Dn, D3);
  transpose_cvt_fp8<<<dim3(32, 32), dim3(32, 8), 0, stream>>>(Wo, Wto8, Dn, Dn);

  gemm_fp8<true><<<dim3(64, 12), dim3(512), 0, stream>>>(Xf8, Wtq8, bqkv, (void*)QKVb, D3, Dn);
  attn_lpt<<<dim3(64, 16), dim3(256), 0, stream>>>(QKVb, Attnb);
  gemm_fp8<false><<<dim3(64, 4), dim3(512), 0, stream>>>(Attnb, Wto8, bo, d_out, Dn, Dn);
  copy_len<<<dim3(1), dim3(64), 0, stream>>>(slen, out + (size_t)Mrows * Dn, Bn);
}

// Round 22
// 154.782 us; speedup vs baseline: 1.9064x; 1.9064x over previous
//
#include <hip/hip_runtime.h>
#include <hip/hip_fp8.h>
#include <stdint.h>

typedef __attribute__((ext_vector_type(8))) short bf16x8;
typedef __attribute__((ext_vector_type(4))) float f32x4;
typedef __attribute__((ext_vector_type(16))) float f32x16;
typedef __attribute__((ext_vector_type(4))) unsigned short u16x4;

static constexpr int Bn = 4, Sn = 2048, Dn = 1024, Hn = 16, HD = 64;
static constexpr int Mrows = Bn * Sn;   // 8192
static constexpr int D3 = 3 * Dn;       // 3072

__device__ __forceinline__ unsigned short f2bf(float f) {
  unsigned int u = __float_as_uint(f);
  u += 0x7FFF + ((u >> 16) & 1);
  return (unsigned short)(u >> 16);
}

__device__ __forceinline__ unsigned char f2fp8(float f) {
  __hip_fp8_e4m3 v(f);
  return (unsigned char)v.__x;
}

__device__ __forceinline__ void gload16(const void* gptr, void* lptr) {
  __builtin_amdgcn_global_load_lds(
      (__attribute__((address_space(1))) void*)gptr,
      (__attribute__((address_space(3))) void*)lptr, 16, 0, 0);
}

__device__ __forceinline__ int swz8(int r) { return (r ^ (r >> 3)) & 7; }

__device__ __forceinline__ float vexp2(float x) {
#if __has_builtin(__builtin_amdgcn_exp2f)
  return __builtin_amdgcn_exp2f(x);
#else
  return exp2f(x);
#endif
}

__device__ __forceinline__ unsigned cvtpk(float lo, float hi) {
  unsigned r;
  asm("v_cvt_pk_bf16_f32 %0, %1, %2" : "=v"(r) : "v"(lo), "v"(hi));
  return r;
}

__device__ __forceinline__ float lanepull(float v, int srclane) {
  return __int_as_float(__builtin_amdgcn_ds_bpermute(srclane * 4, __float_as_int(v)));
}

// ---------------- elementwise f32 -> fp8 e4m3 ----------------
__global__ void cvt_f32_fp8(const float* __restrict__ in,
                            unsigned char* __restrict__ out, int n) {
  int i = (blockIdx.x * blockDim.x + threadIdx.x) * 4;
  if (i < n) {
    const float4 v = *(const float4*)(in + i);
    uchar4 o;
    o.x = f2fp8(v.x); o.y = f2fp8(v.y); o.z = f2fp8(v.z); o.w = f2fp8(v.w);
    *(uchar4*)(out + i) = o;
  }
}

// ---------------- W [K][N] f32 -> W^T [N][K] fp8 (scaled x64) ----------------
__global__ void transpose_cvt_fp8(const float* __restrict__ W,
                                  unsigned char* __restrict__ Wt, int K, int N) {
  __shared__ float tile[32][33];
  const int n0 = blockIdx.x * 32, k0 = blockIdx.y * 32;
  const int tx = threadIdx.x, ty = threadIdx.y;   // block (32,8)
  #pragma unroll
  for (int j = 0; j < 4; j++)
    tile[ty + 8 * j][tx] = W[(size_t)(k0 + ty + 8 * j) * N + n0 + tx];
  __syncthreads();
  #pragma unroll
  for (int j = 0; j < 4; j++)
    Wt[(size_t)(n0 + ty + 8 * j) * K + k0 + tx] = f2fp8(tile[tx][ty + 8 * j] * 64.0f);
}

// ---------------- 128x256 fp8 GEMM, BK=128 (round-19/20 proven) ----------------
template<bool BF16_OUT>
__global__ __launch_bounds__(512, 1)
void gemm_fp8(const unsigned char* __restrict__ A,
              const unsigned char* __restrict__ Bt,
              const float* __restrict__ bias,
              void* __restrict__ Cout, int Nt, int Kt) {
  __shared__ __align__(128) unsigned char smem[98304];  // 2 x (A 16K + B 32K)
  const int tid = threadIdx.x;
  const int w = tid >> 6, lane = tid & 63;
  const int wm = w >> 2, wn = w & 3;
  const int lrow = lane & 15, lk = lane >> 4;
  const long brow = (long)blockIdx.x * 128;
  const long bcol = (long)blockIdx.y * 256;

  const int srow = tid >> 3;    // 0..63
  const int sslot = tid & 7;

  auto stage = [&](int k0, unsigned char* buf) {   // 6 gloads: 2 A + 4 B
    unsigned char* Ab = buf;
    unsigned char* Bb = buf + 16384;
    #pragma unroll
    for (int i = 0; i < 2; i++) {
      const int r = srow + 64 * i;
      gload16(A + (size_t)(brow + r) * Kt + k0 + ((sslot ^ swz8(r)) * 16),
              Ab + w * 1024 + i * 8192);
    }
    #pragma unroll
    for (int i = 0; i < 4; i++) {
      const int r = srow + 64 * i;
      gload16(Bt + (size_t)(bcol + r) * Kt + k0 + ((sslot ^ swz8(r)) * 16),
              Bb + w * 1024 + i * 8192);
    }
  };

  f32x4 acc[4][4] = {};

  stage(0, smem);

  const int ntile = Kt >> 7;          // BK = 128
  for (int t = 0; t < ntile; t++) {
    const int cur = t & 1;
    unsigned char* Ab = smem + cur * 49152;
    unsigned char* Bb = Ab + 16384;

    __builtin_amdgcn_s_barrier();     // retires t-1 readers of buf^1
    if (t + 1 < ntile) {
      stage((t + 1) << 7, smem + (cur ^ 1) * 49152);
      asm volatile("s_waitcnt vmcnt(6)");  // t's 6 loads done; t+1's in flight
    } else {
      asm volatile("s_waitcnt vmcnt(0)");
    }
    __builtin_amdgcn_sched_barrier(0);
    __builtin_amdgcn_s_barrier();     // buf t visible block-wide

    const int sub = (lk & 1) * 8;
    #pragma unroll
    for (int kk = 0; kk < 4; kk++) {
      const int s16 = kk * 2 + (lk >> 1);
      long av[4], bv[4];
      #pragma unroll
      for (int mt = 0; mt < 4; mt++) {
        const int r = wm * 64 + mt * 16 + lrow;
        av[mt] = *(const long*)(Ab + r * 128 + (((s16 ^ swz8(r)) << 4) + sub));
      }
      #pragma unroll
      for (int nt = 0; nt < 4; nt++) {
        const int r = wn * 64 + nt * 16 + lrow;
        bv[nt] = *(const long*)(Bb + r * 128 + (((s16 ^ swz8(r)) << 4) + sub));
      }
      __builtin_amdgcn_s_setprio(1);
      #pragma unroll
      for (int mt = 0; mt < 4; mt++)
        #pragma unroll
        for (int nt = 0; nt < 4; nt++)
          acc[mt][nt] = __builtin_amdgcn_mfma_f32_16x16x32_fp8_fp8(av[mt], bv[nt], acc[mt][nt], 0, 0, 0);
      __builtin_amdgcn_s_setprio(0);
    }
  }

  #pragma unroll
  for (int nt = 0; nt < 4; nt++) {
    const long col = bcol + wn * 64 + nt * 16 + lrow;
    const float bv2 = bias[col];
    #pragma unroll
    for (int mt = 0; mt < 4; mt++) {
      #pragma unroll
      for (int rr = 0; rr < 4; rr++) {
        const long row = brow + wm * 64 + mt * 16 + lk * 4 + rr;
        const float v = acc[mt][nt][rr] * 0.015625f + bv2;
        if (BF16_OUT)
          ((unsigned short*)Cout)[row * Nt + col] = f2bf(v);
        else
          ((float*)Cout)[row * Nt + col] = v;
      }
    }
  }
}

// ---------------- flash attention: LPT 4-wave blocks ----------------
// Block = (bh, y): m = 15-y (LPT: heaviest first), owns 128 q-rows
// [128m, 128m+128); wave w -> 32-row subtile. 1024 blocks; natural VGPR
// (~100-120) -> 4 waves/SIMD -> 4 blocks/CU resident (LDS 4x32KB=128<=160).
// launch_bounds(256,2): ROUND-21 LESSON — (256,4) forced VGPR cap 64 and
// spilled 160 MB to scratch (2.9x regression); never force residency via
// launch_bounds beyond natural allocation.
// KV tile = 128 rows, SINGLE-buffered, 2 barriers/tile; K via gload_lds
// (pre-swizzled source), VT reg-staged scatter (r18-verbatim formulas).
// Epilogue emits fp8 e4m3 (feeds fp8 proj GEMM).
__global__ __launch_bounds__(256, 2)
void attn_lpt(const unsigned short* __restrict__ QKV,
              unsigned char* __restrict__ Out) {
  __shared__ __align__(128) unsigned char smem[32768]; // 16K K + 16K VT
  const int tid  = threadIdx.x;
  const int w    = tid >> 6;
  const int lane = tid & 63;
  const int li = lane & 31, hi = lane >> 5;
  const int bh = blockIdx.x;
  const int b  = bh >> 4, h = bh & 15;
  const int m  = 15 - (int)blockIdx.y;       // LPT: longest blocks dispatch first
  const int wq = m * 128 + w * 32;
  const int qrow = wq + li;

  const float cexp = 0.18033688011112042f;   // (1/8) * log2(e)

  bf16x8 qf[4];
  {
    const unsigned short* qp = QKV + (size_t)(b * Sn + qrow) * D3 + h * HD + hi * 8;
    #pragma unroll
    for (int ks = 0; ks < 4; ks++) qf[ks] = *(const bf16x8*)(qp + ks * 16);
  }

  f32x16 o0 = {}, o1 = {};
  float mm = -3.0e38f, ls = 0.f;

  unsigned char* Kb = smem;
  unsigned char* Vb = smem + 16384;

  // K stage: 4 gload rounds; round i covers rows [32i, 32i+32)
  auto kstage = [&](int kb) {
    #pragma unroll
    for (int i = 0; i < 4; i++) {
      const int r    = i * 32 + w * 8 + (lane >> 3);
      const int slot = (lane & 7) ^ swz8(r);
      gload16(QKV + (size_t)(b * Sn + kb + r) * D3 + Dn + h * HD + slot * 8,
              Kb + i * 4096 + w * 1024);
    }
  };
  const int vkv = tid >> 1;           // 0..127
  const int vd0 = (tid & 1) * 32;
  auto vload = [&](int kb, int jj) -> bf16x8 {
    return *(const bf16x8*)(QKV + (size_t)(b * Sn + kb + vkv) * D3 + 2 * Dn + h * HD + vd0 + jj * 8);
  };
  auto vwrite = [&](bf16x8 vv, int jj) {
    #pragma unroll
    for (int e = 0; e < 8; e++) {
      const int d  = vd0 + jj * 8 + e;
      const int vs = (d ^ (d >> 3)) & 15;
      *(unsigned short*)(Vb + d * 256 + (((vkv >> 3) ^ vs) << 4) + (vkv & 7) * 2) = (unsigned short)vv[e];
    }
  };

  // one 64-kv online-softmax sub-step (r18-verbatim)
  auto substep = [&](int s, int kb) {
    f32x16 s0 = {}, s1 = {};
    const int r0 = s * 64 + li, r1 = s * 64 + 32 + li;
    __builtin_amdgcn_s_setprio(1);
    #pragma unroll
    for (int ks = 0; ks < 4; ks++) {
      const int slot = ks * 2 + hi;
      const bf16x8 k0 = *(const bf16x8*)(Kb + r0 * 128 + ((slot ^ swz8(r0)) * 16));
      const bf16x8 k1 = *(const bf16x8*)(Kb + r1 * 128 + ((slot ^ swz8(r1)) * 16));
      s0 = __builtin_amdgcn_mfma_f32_32x32x16_bf16(k0, qf[ks], s0, 0, 0, 0);
      s1 = __builtin_amdgcn_mfma_f32_32x32x16_bf16(k1, qf[ks], s1, 0, 0, 0);
    }
    __builtin_amdgcn_s_setprio(0);
    const int kbase = kb + s * 64;
    if (kbase + 63 > wq) {   // diagonal: mask
      #pragma unroll
      for (int r = 0; r < 16; r++) {
        const int kvl = (r & 3) + 8 * (r >> 2) + 4 * hi;
        if (kbase + kvl > qrow)      s0[r] = -3.0e38f;
        if (kbase + 32 + kvl > qrow) s1[r] = -3.0e38f;
      }
    }
    float t8[8];
    #pragma unroll
    for (int r = 0; r < 8; r++)
      t8[r] = fmaxf(fmaxf(s0[r], s0[r + 8]), fmaxf(s1[r], s1[r + 8]));
    float tmax = fmaxf(fmaxf(fmaxf(t8[0], t8[1]), fmaxf(t8[2], t8[3])),
                       fmaxf(fmaxf(t8[4], t8[5]), fmaxf(t8[6], t8[7])));
    tmax = fmaxf(tmax, __shfl_xor(tmax, 32));
    if (__any(tmax > mm + 44.0f)) {   // defer-max
      const float mn   = fmaxf(mm, tmax);
      const float corr = vexp2((mm - mn) * cexp);
      mm = mn;
      ls *= corr;
      #pragma unroll
      for (int r = 0; r < 16; r++) {
        const float cr = lanepull(corr, (r & 3) + 8 * (r >> 2) + 4 * hi);
        o0[r] *= cr; o1[r] *= cr;
      }
    }
    const float mc = mm * cexp;
    f32x16 p0, p1;
    float psa = 0.f, psb = 0.f, psc = 0.f, psd = 0.f;
    #pragma unroll
    for (int r = 0; r < 16; r += 4) {
      p0[r] = vexp2(fmaf(s0[r], cexp, -mc));         psa += p0[r];
      p0[r + 1] = vexp2(fmaf(s0[r + 1], cexp, -mc)); psb += p0[r + 1];
      p0[r + 2] = vexp2(fmaf(s0[r + 2], cexp, -mc)); psc += p0[r + 2];
      p0[r + 3] = vexp2(fmaf(s0[r + 3], cexp, -mc)); psd += p0[r + 3];
    }
    #pragma unroll
    for (int r = 0; r < 16; r += 4) {
      p1[r] = vexp2(fmaf(s1[r], cexp, -mc));         psa += p1[r];
      p1[r + 1] = vexp2(fmaf(s1[r + 1], cexp, -mc)); psb += p1[r + 1];
      p1[r + 2] = vexp2(fmaf(s1[r + 2], cexp, -mc)); psc += p1[r + 2];
      p1[r + 3] = vexp2(fmaf(s1[r + 3], cexp, -mc)); psd += p1[r + 3];
    }
    ls += (psa + psb) + (psc + psd);

    auto mk_pa = [&](const f32x16& pp, int base) -> bf16x8 {
      const unsigned a0 = cvtpk(pp[base + 0], pp[base + 1]);
      const unsigned a1 = cvtpk(pp[base + 2], pp[base + 3]);
      const unsigned b0 = cvtpk(pp[base + 4], pp[base + 5]);
      const unsigned b1 = cvtpk(pp[base + 6], pp[base + 7]);
      const unsigned xa0 = __shfl_xor(a0, 32), xa1 = __shfl_xor(a1, 32);
      const unsigned xb0 = __shfl_xor(b0, 32), xb1 = __shfl_xor(b1, 32);
      union { unsigned u[4]; bf16x8 v; } pu;
      pu.u[0] = hi ? xb0 : a0;
      pu.u[1] = hi ? xb1 : a1;
      pu.u[2] = hi ? b0  : xa0;
      pu.u[3] = hi ? b1  : xa1;
      return pu.v;
    };
    bf16x8 pa[4];
    pa[0] = mk_pa(p0, 0); pa[1] = mk_pa(p0, 8);
    pa[2] = mk_pa(p1, 0); pa[3] = mk_pa(p1, 8);

    const int vs0 = (li ^ (li >> 3)) & 15;
    const int vs1 = ((32 + li) ^ ((32 + li) >> 3)) & 15;
    __builtin_amdgcn_s_setprio(1);
    #pragma unroll
    for (int k16 = 0; k16 < 4; k16++) {
      const int slot = s * 8 + k16 * 2 + hi;
      const bf16x8 vb0 = *(const bf16x8*)(Vb + li * 256 + ((slot ^ vs0) << 4));
      const bf16x8 vb1 = *(const bf16x8*)(Vb + (32 + li) * 256 + ((slot ^ vs1) << 4));
      o0 = __builtin_amdgcn_mfma_f32_32x32x16_bf16(pa[k16], vb0, o0, 0, 0, 0);
      o1 = __builtin_amdgcn_mfma_f32_32x32x16_bf16(pa[k16], vb1, o1, 0, 0, 0);
    }
    __builtin_amdgcn_s_setprio(0);
  };

  for (int t = 0; t <= m; t++) {
    const int kb = t << 7;
    __builtin_amdgcn_s_barrier();     // all waves done reading previous tile
    kstage(kb);                        // K -> LDS (async)
    {
      bf16x8 v0 = vload(kb, 0), v1 = vload(kb, 1), v2 = vload(kb, 2), v3 = vload(kb, 3);
      vwrite(v0, 0); vwrite(v1, 1); vwrite(v2, 2); vwrite(v3, 3);  // reg deps drain V
    }
    asm volatile("s_waitcnt vmcnt(0) lgkmcnt(0)");  // K LDS-writes + V ds_writes done
    __builtin_amdgcn_sched_barrier(0);
    __builtin_amdgcn_s_barrier();     // tile visible block-wide

    substep(0, kb);
    if (kb + 64 <= wq + 31) substep(1, kb);
  }

  // ---- epilogue: O / l -> fp8 e4m3 ----
  const float lt = ls + __shfl_xor(ls, 32);
  const float rl = __builtin_amdgcn_rcpf(lt);
  #pragma unroll
  for (int r = 0; r < 16; r++) {
    const int q = (r & 3) + 8 * (r >> 2) + 4 * hi;
    const float rr = lanepull(rl, q);
    unsigned char* op = Out + (size_t)(b * Sn + wq + q) * Dn + h * HD;
    op[li]      = f2fp8(o0[r] * rr);
    op[32 + li] = f2fp8(o1[r] * rr);
  }
}

// ---------------- tail: string_len -> float ----------------
__global__ void copy_len(const int* __restrict__ slen, float* __restrict__ dst, int n) {
  const int i = threadIdx.x;
  if (i < n) dst[i] = (float)slen[i];
}

extern "C" void kernel_launch(void* const* d_in, const int* in_sizes, int n_in,
                              void* d_out, int out_size, void* d_ws, size_t ws_size,
                              hipStream_t stream) {
  const float* X    = (const float*)d_in[0];
  const int*   slen = (const int*)d_in[1];
  const float* Wqkv = (const float*)d_in[2];
  const float* bqkv = (const float*)d_in[3];
  const float* Wo   = (const float*)d_in[4];
  const float* bo   = (const float*)d_in[5];
  float* out = (float*)d_out;

  char* ws = (char*)d_ws;
  unsigned char*  Xf8   = (unsigned char*)ws;                        // 8.4 MB (region 16 MB)
  unsigned char*  Wtq8  = (unsigned char*)(ws + 16777216);           // 3.1 MB (region 6 MB)
  unsigned char*  Wto8  = (unsigned char*)(ws + 16777216 + 6291456); // 1.05 MB (region 2 MB)
  unsigned short* QKVb  = (unsigned short*)(ws + 16777216 + 6291456 + 2097152);
  unsigned char*  Attnb = (unsigned char*)ws;   // X dead after QKV GEMM; reuse (fp8)

  cvt_f32_fp8<<<dim3(8192), dim3(256), 0, stream>>>(X, Xf8, Mrows * Dn);
  transpose_cvt_fp8<<<dim3(96, 32), dim3(32, 8), 0, stream>>>(Wqkv, Wtq8, Dn, D3);
  transpose_cvt_fp8<<<dim3(32, 32), dim3(32, 8), 0, stream>>>(Wo, Wto8, Dn, Dn);

  gemm_fp8<true><<<dim3(64, 12), dim3(512), 0, stream>>>(Xf8, Wtq8, bqkv, (void*)QKVb, D3, Dn);
  attn_lpt<<<dim3(64, 16), dim3(256), 0, stream>>>(QKVb, Attnb);
  gemm_fp8<false><<<dim3(64, 4), dim3(512), 0, stream>>>(Attnb, Wto8, bo, d_out, Dn, Dn);
  copy_len<<<dim3(1), dim3(64), 0, stream>>>(slen, out + (size_t)Mrows * Dn, Bn);
}

// Round 23
// 151.663 us; speedup vs baseline: 1.9456x; 1.0206x over previous
//
#include <hip/hip_runtime.h>
#include <hip/hip_fp8.h>
#include <stdint.h>

typedef __attribute__((ext_vector_type(8))) short bf16x8;
typedef __attribute__((ext_vector_type(4))) float f32x4;
typedef __attribute__((ext_vector_type(16))) float f32x16;
typedef __attribute__((ext_vector_type(4))) unsigned short u16x4;

static constexpr int Bn = 4, Sn = 2048, Dn = 1024, Hn = 16, HD = 64;
static constexpr int Mrows = Bn * Sn;   // 8192
static constexpr int D3 = 3 * Dn;       // 3072

__device__ __forceinline__ unsigned short f2bf(float f) {
  unsigned int u = __float_as_uint(f);
  u += 0x7FFF + ((u >> 16) & 1);
  return (unsigned short)(u >> 16);
}

__device__ __forceinline__ unsigned char f2fp8(float f) {
  __hip_fp8_e4m3 v(f);
  return (unsigned char)v.__x;
}

__device__ __forceinline__ void gload16(const void* gptr, void* lptr) {
  __builtin_amdgcn_global_load_lds(
      (__attribute__((address_space(1))) void*)gptr,
      (__attribute__((address_space(3))) void*)lptr, 16, 0, 0);
}

__device__ __forceinline__ int swz8(int r) { return (r ^ (r >> 3)) & 7; }

__device__ __forceinline__ float vexp2(float x) {
#if __has_builtin(__builtin_amdgcn_exp2f)
  return __builtin_amdgcn_exp2f(x);
#else
  return exp2f(x);
#endif
}

__device__ __forceinline__ unsigned cvtpk(float lo, float hi) {
  unsigned r;
  asm("v_cvt_pk_bf16_f32 %0, %1, %2" : "=v"(r) : "v"(lo), "v"(hi));
  return r;
}

__device__ __forceinline__ float lanepull(float v, int srclane) {
  return __int_as_float(__builtin_amdgcn_ds_bpermute(srclane * 4, __float_as_int(v)));
}

// ---------------- elementwise f32 -> fp8 e4m3 ----------------
__global__ void cvt_f32_fp8(const float* __restrict__ in,
                            unsigned char* __restrict__ out, int n) {
  int i = (blockIdx.x * blockDim.x + threadIdx.x) * 4;
  if (i < n) {
    const float4 v = *(const float4*)(in + i);
    uchar4 o;
    o.x = f2fp8(v.x); o.y = f2fp8(v.y); o.z = f2fp8(v.z); o.w = f2fp8(v.w);
    *(uchar4*)(out + i) = o;
  }
}

// ---------------- W [K][N] f32 -> W^T [N][K] fp8 (scaled x64) ----------------
__global__ void transpose_cvt_fp8(const float* __restrict__ W,
                                  unsigned char* __restrict__ Wt, int K, int N) {
  __shared__ float tile[32][33];
  const int n0 = blockIdx.x * 32, k0 = blockIdx.y * 32;
  const int tx = threadIdx.x, ty = threadIdx.y;   // block (32,8)
  #pragma unroll
  for (int j = 0; j < 4; j++)
    tile[ty + 8 * j][tx] = W[(size_t)(k0 + ty + 8 * j) * N + n0 + tx];
  __syncthreads();
  #pragma unroll
  for (int j = 0; j < 4; j++)
    Wt[(size_t)(n0 + ty + 8 * j) * K + k0 + tx] = f2fp8(tile[tx][ty + 8 * j] * 64.0f);
}

// ---------------- 128x256 fp8 GEMM, BK=128: C = A[M,K] @ (64*Bt)[N,K]^T /64 + bias ----------------
// bt2 staging frame (128-B rows, swz8 16B-slot swizzle, 6 gloads, counted
// vmcnt(6), 2-barrier loop); rows hold 128 fp8 -> BK=128 (8 iters at K=1024).
// 64 MFMA/wave/iter via mfma_f32_16x16x32_fp8_fp8 (b64 frags).
// Epilogue un-scales W's x64 (acc * 1/64) then adds bias.
template<bool BF16_OUT>
__global__ __launch_bounds__(512, 1)
void gemm_fp8(const unsigned char* __restrict__ A,
              const unsigned char* __restrict__ Bt,
              const float* __restrict__ bias,
              void* __restrict__ Cout, int Nt, int Kt) {
  __shared__ __align__(128) unsigned char smem[98304];  // 2 x (A 16K + B 32K)
  const int tid = threadIdx.x;
  const int w = tid >> 6, lane = tid & 63;
  const int wm = w >> 2, wn = w & 3;
  const int lrow = lane & 15, lk = lane >> 4;
  const long brow = (long)blockIdx.x * 128;
  const long bcol = (long)blockIdx.y * 256;

  const int srow = tid >> 3;    // 0..63
  const int sslot = tid & 7;

  auto stage = [&](int k0, unsigned char* buf) {   // 6 gloads: 2 A + 4 B
    unsigned char* Ab = buf;
    unsigned char* Bb = buf + 16384;
    #pragma unroll
    for (int i = 0; i < 2; i++) {
      const int r = srow + 64 * i;
      gload16(A + (size_t)(brow + r) * Kt + k0 + ((sslot ^ swz8(r)) * 16),
              Ab + w * 1024 + i * 8192);
    }
    #pragma unroll
    for (int i = 0; i < 4; i++) {
      const int r = srow + 64 * i;
      gload16(Bt + (size_t)(bcol + r) * Kt + k0 + ((sslot ^ swz8(r)) * 16),
              Bb + w * 1024 + i * 8192);
    }
  };

  f32x4 acc[4][4] = {};

  stage(0, smem);

  const int ntile = Kt >> 7;          // BK = 128
  for (int t = 0; t < ntile; t++) {
    const int cur = t & 1;
    unsigned char* Ab = smem + cur * 49152;
    unsigned char* Bb = Ab + 16384;

    __builtin_amdgcn_s_barrier();     // retires t-1 readers of buf^1
    if (t + 1 < ntile) {
      stage((t + 1) << 7, smem + (cur ^ 1) * 49152);
      asm volatile("s_waitcnt vmcnt(6)");  // t's 6 loads done; t+1's in flight
    } else {
      asm volatile("s_waitcnt vmcnt(0)");
    }
    __builtin_amdgcn_sched_barrier(0);
    __builtin_amdgcn_s_barrier();     // buf t visible block-wide

    const int sub = (lk & 1) * 8;
    #pragma unroll
    for (int kk = 0; kk < 4; kk++) {
      const int s16 = kk * 2 + (lk >> 1);
      long av[4], bv[4];
      #pragma unroll
      for (int mt = 0; mt < 4; mt++) {
        const int r = wm * 64 + mt * 16 + lrow;
        av[mt] = *(const long*)(Ab + r * 128 + (((s16 ^ swz8(r)) << 4) + sub));
      }
      #pragma unroll
      for (int nt = 0; nt < 4; nt++) {
        const int r = wn * 64 + nt * 16 + lrow;
        bv[nt] = *(const long*)(Bb + r * 128 + (((s16 ^ swz8(r)) << 4) + sub));
      }
      __builtin_amdgcn_s_setprio(1);
      #pragma unroll
      for (int mt = 0; mt < 4; mt++)
        #pragma unroll
        for (int nt = 0; nt < 4; nt++)
          acc[mt][nt] = __builtin_amdgcn_mfma_f32_16x16x32_fp8_fp8(av[mt], bv[nt], acc[mt][nt], 0, 0, 0);
      __builtin_amdgcn_s_setprio(0);
    }
  }

  #pragma unroll
  for (int nt = 0; nt < 4; nt++) {
    const long col = bcol + wn * 64 + nt * 16 + lrow;
    const float bv2 = bias[col];
    #pragma unroll
    for (int mt = 0; mt < 4; mt++) {
      #pragma unroll
      for (int rr = 0; rr < 4; rr++) {
        const long row = brow + wm * 64 + mt * 16 + lk * 4 + rr;
        const float v = acc[mt][nt][rr] * 0.015625f + bv2;
        if (BF16_OUT)
          ((unsigned short*)Cout)[row * Nt + col] = f2bf(v);
        else
          ((float*)Cout)[row * Nt + col] = v;
      }
    }
  }
}

// ---------------- flash attention: sequential-pair balanced schedule ----------------
// (round-18 verified structure; epilogue emits fp8 e4m3 for the proj GEMM)
// Block = (bh, p): q-tiles HEAVY=(7-p)*256 and LIGHT=p*256 rows processed
// sequentially over ONE shared KV stream -> uniform 18 tile-units/block.
// Six occupancy/schedule variants tested (r6-r22); this is the floor.
__global__ __launch_bounds__(512, 1)
void attn_pair(const unsigned short* __restrict__ QKV,
               unsigned char* __restrict__ Out) {
  __shared__ __align__(128) unsigned char smem[65536]; // 2 x (16K K + 16K VT)
  const int tid  = threadIdx.x;
  const int w    = tid >> 6;
  const int lane = tid & 63;
  const int li = lane & 31, hi = lane >> 5;
  const int bh = blockIdx.x;
  const int b  = bh >> 4, h = bh & 15;
  const int p  = blockIdx.y;                 // pair index 0..3
  const int wqh = (7 - p) * 256 + w * 32;    // heavy subtile base
  const int wql = p * 256 + w * 32;          // light subtile base

  const float cexp = 0.18033688011112042f;   // (1/8) * log2(e)

  bf16x8 qfh[4], qfl[4];
  {
    const unsigned short* qp = QKV + (size_t)(b * Sn + wqh + li) * D3 + h * HD + hi * 8;
    #pragma unroll
    for (int ks = 0; ks < 4; ks++) qfh[ks] = *(const bf16x8*)(qp + ks * 16);
  }
  {
    const unsigned short* qp = QKV + (size_t)(b * Sn + wql + li) * D3 + h * HD + hi * 8;
    #pragma unroll
    for (int ks = 0; ks < 4; ks++) qfl[ks] = *(const bf16x8*)(qp + ks * 16);
  }

  f32x16 o0h = {}, o1h = {}, o0l = {}, o1l = {};
  float mh = -3.0e38f, lsh = 0.f, ml = -3.0e38f, lsl = 0.f;

  auto kstage = [&](int kb, unsigned char* Kb) {
    #pragma unroll
    for (int i = 0; i < 2; i++) {
      const int r    = w * 16 + i * 8 + (lane >> 3);
      const int slot = (lane & 7) ^ swz8(r);
      gload16(QKV + (size_t)(b * Sn + kb + r) * D3 + Dn + h * HD + slot * 8,
              Kb + w * 2048 + i * 1024);
    }
  };
  const int vkv8 = tid >> 3;          // 0..63
  const int vd0  = (tid & 7) * 8;
  auto vload = [&](int kb, int i) -> bf16x8 {
    return *(const bf16x8*)(QKV + (size_t)(b * Sn + kb + i * 64 + vkv8) * D3 + 2 * Dn + h * HD + vd0);
  };
  auto vwrite = [&](bf16x8 vv, int i, unsigned char* Vb) {
    const int kv = i * 64 + vkv8;
    #pragma unroll
    for (int jj = 0; jj < 8; jj++) {
      const int d  = vd0 + jj;
      const int vs = (d ^ (d >> 3)) & 15;
      *(unsigned short*)(Vb + d * 256 + (((kv >> 3) ^ vs) << 4) + (kv & 7) * 2) = (unsigned short)vv[jj];
    }
  };

  auto substep = [&](int s, int kb, const unsigned char* Kb, const unsigned char* Vb,
                     int wqX, bf16x8 (&qf)[4], f32x16& o0, f32x16& o1,
                     float& m, float& ls) {
    const int qrowX = wqX + li;
    f32x16 s0 = {}, s1 = {};
    const int r0 = s * 64 + li, r1 = s * 64 + 32 + li;
    __builtin_amdgcn_s_setprio(1);
    #pragma unroll
    for (int ks = 0; ks < 4; ks++) {
      const int slot = ks * 2 + hi;
      const bf16x8 k0 = *(const bf16x8*)(Kb + r0 * 128 + ((slot ^ swz8(r0)) * 16));
      const bf16x8 k1 = *(const bf16x8*)(Kb + r1 * 128 + ((slot ^ swz8(r1)) * 16));
      s0 = __builtin_amdgcn_mfma_f32_32x32x16_bf16(k0, qf[ks], s0, 0, 0, 0);
      s1 = __builtin_amdgcn_mfma_f32_32x32x16_bf16(k1, qf[ks], s1, 0, 0, 0);
    }
    __builtin_amdgcn_s_setprio(0);
    const int kbase = kb + s * 64;
    if (kbase + 63 > wqX) {
      #pragma unroll
      for (int r = 0; r < 16; r++) {
        const int kvl = (r & 3) + 8 * (r >> 2) + 4 * hi;
        if (kbase + kvl > qrowX)      s0[r] = -3.0e38f;
        if (kbase + 32 + kvl > qrowX) s1[r] = -3.0e38f;
      }
    }
    float t8[8];
    #pragma unroll
    for (int r = 0; r < 8; r++)
      t8[r] = fmaxf(fmaxf(s0[r], s0[r + 8]), fmaxf(s1[r], s1[r + 8]));
    float tmax = fmaxf(fmaxf(fmaxf(t8[0], t8[1]), fmaxf(t8[2], t8[3])),
                       fmaxf(fmaxf(t8[4], t8[5]), fmaxf(t8[6], t8[7])));
    tmax = fmaxf(tmax, __shfl_xor(tmax, 32));
    if (__any(tmax > m + 44.0f)) {
      const float mn   = fmaxf(m, tmax);
      const float corr = vexp2((m - mn) * cexp);
      m = mn;
      ls *= corr;
      #pragma unroll
      for (int r = 0; r < 16; r++) {
        const float cr = lanepull(corr, (r & 3) + 8 * (r >> 2) + 4 * hi);
        o0[r] *= cr; o1[r] *= cr;
      }
    }
    const float mc = m * cexp;
    f32x16 p0, p1;
    float psa = 0.f, psb = 0.f, psc = 0.f, psd = 0.f;
    #pragma unroll
    for (int r = 0; r < 16; r += 4) {
      p0[r] = vexp2(fmaf(s0[r], cexp, -mc));         psa += p0[r];
      p0[r + 1] = vexp2(fmaf(s0[r + 1], cexp, -mc)); psb += p0[r + 1];
      p0[r + 2] = vexp2(fmaf(s0[r + 2], cexp, -mc)); psc += p0[r + 2];
      p0[r + 3] = vexp2(fmaf(s0[r + 3], cexp, -mc)); psd += p0[r + 3];
    }
    #pragma unroll
    for (int r = 0; r < 16; r += 4) {
      p1[r] = vexp2(fmaf(s1[r], cexp, -mc));         psa += p1[r];
      p1[r + 1] = vexp2(fmaf(s1[r + 1], cexp, -mc)); psb += p1[r + 1];
      p1[r + 2] = vexp2(fmaf(s1[r + 2], cexp, -mc)); psc += p1[r + 2];
      p1[r + 3] = vexp2(fmaf(s1[r + 3], cexp, -mc)); psd += p1[r + 3];
    }
    ls += (psa + psb) + (psc + psd);

    auto mk_pa = [&](const f32x16& pp, int base) -> bf16x8 {
      const unsigned a0 = cvtpk(pp[base + 0], pp[base + 1]);
      const unsigned a1 = cvtpk(pp[base + 2], pp[base + 3]);
      const unsigned b0 = cvtpk(pp[base + 4], pp[base + 5]);
      const unsigned b1 = cvtpk(pp[base + 6], pp[base + 7]);
      const unsigned xa0 = __shfl_xor(a0, 32), xa1 = __shfl_xor(a1, 32);
      const unsigned xb0 = __shfl_xor(b0, 32), xb1 = __shfl_xor(b1, 32);
      union { unsigned u[4]; bf16x8 v; } pu;
      pu.u[0] = hi ? xb0 : a0;
      pu.u[1] = hi ? xb1 : a1;
      pu.u[2] = hi ? b0  : xa0;
      pu.u[3] = hi ? b1  : xa1;
      return pu.v;
    };
    bf16x8 pa[4];
    pa[0] = mk_pa(p0, 0); pa[1] = mk_pa(p0, 8);
    pa[2] = mk_pa(p1, 0); pa[3] = mk_pa(p1, 8);

    const int vs0 = (li ^ (li >> 3)) & 15;
    const int vs1 = ((32 + li) ^ ((32 + li) >> 3)) & 15;
    __builtin_amdgcn_s_setprio(1);
    #pragma unroll
    for (int k16 = 0; k16 < 4; k16++) {
      const int slot = s * 8 + k16 * 2 + hi;
      const bf16x8 vb0 = *(const bf16x8*)(Vb + li * 256 + ((slot ^ vs0) << 4));
      const bf16x8 vb1 = *(const bf16x8*)(Vb + (32 + li) * 256 + ((slot ^ vs1) << 4));
      o0 = __builtin_amdgcn_mfma_f32_32x32x16_bf16(pa[k16], vb0, o0, 0, 0, 0);
      o1 = __builtin_amdgcn_mfma_f32_32x32x16_bf16(pa[k16], vb1, o1, 0, 0, 0);
    }
    __builtin_amdgcn_s_setprio(0);
  };

  kstage(0, smem);
  {
    bf16x8 va = vload(0, 0), vb = vload(0, 1);
    vwrite(va, 0, smem + 16384);
    vwrite(vb, 1, smem + 16384);
  }
  asm volatile("s_waitcnt lgkmcnt(0)");
  __builtin_amdgcn_sched_barrier(0);

  const int nt = 16 - 2 * p;   // tiles needed by the heavy q-tile
  for (int t = 0; t < nt; t++) {
    const int kb  = t << 7;
    const int cur = t & 1;
    unsigned char* Kb = smem + cur * 32768;
    unsigned char* Vb = Kb + 16384;
    const bool pre = (t + 1 < nt);
    bf16x8 vna, vnb;

    __builtin_amdgcn_s_barrier();
    if (pre) {
      kstage(kb + 128, smem + (cur ^ 1) * 32768);
      vna = vload(kb + 128, 0);
      vnb = vload(kb + 128, 1);
    }

    if (kb <= wqh + 31) {
      substep(0, kb, Kb, Vb, wqh, qfh, o0h, o1h, mh, lsh);
      if (kb + 64 <= wqh + 31) substep(1, kb, Kb, Vb, wqh, qfh, o0h, o1h, mh, lsh);
    }
    if (kb <= wql + 31) {
      substep(0, kb, Kb, Vb, wql, qfl, o0l, o1l, ml, lsl);
      if (kb + 64 <= wql + 31) substep(1, kb, Kb, Vb, wql, qfl, o0l, o1l, ml, lsl);
    }

    if (pre) {
      unsigned char* Vn = smem + (cur ^ 1) * 32768 + 16384;
      vwrite(vna, 0, Vn);
      vwrite(vnb, 1, Vn);
    }
    asm volatile("s_waitcnt lgkmcnt(0)");
    __builtin_amdgcn_sched_barrier(0);
  }

  // ---- epilogue: O / l -> fp8 e4m3 (feeds the fp8 proj GEMM) ----
  {
    const float lt = lsh + __shfl_xor(lsh, 32);
    const float rl = __builtin_amdgcn_rcpf(lt);
    #pragma unroll
    for (int r = 0; r < 16; r++) {
      const int q = (r & 3) + 8 * (r >> 2) + 4 * hi;
      const float rr = lanepull(rl, q);
      unsigned char* op = Out + (size_t)(b * Sn + wqh + q) * Dn + h * HD;
      op[li]      = f2fp8(o0h[r] * rr);
      op[32 + li] = f2fp8(o1h[r] * rr);
    }
  }
  {
    const float lt = lsl + __shfl_xor(lsl, 32);
    const float rl = __builtin_amdgcn_rcpf(lt);
    #pragma unroll
    for (int r = 0; r < 16; r++) {
      const int q = (r & 3) + 8 * (r >> 2) + 4 * hi;
      const float rr = lanepull(rl, q);
      unsigned char* op = Out + (size_t)(b * Sn + wql + q) * Dn + h * HD;
      op[li]      = f2fp8(o0l[r] * rr);
      op[32 + li] = f2fp8(o1l[r] * rr);
    }
  }
}

// ---------------- tail: string_len -> float ----------------
__global__ void copy_len(const int* __restrict__ slen, float* __restrict__ dst, int n) {
  const int i = threadIdx.x;
  if (i < n) dst[i] = (float)slen[i];
}

extern "C" void kernel_launch(void* const* d_in, const int* in_sizes, int n_in,
                              void* d_out, int out_size, void* d_ws, size_t ws_size,
                              hipStream_t stream) {
  const float* X    = (const float*)d_in[0];
  const int*   slen = (const int*)d_in[1];
  const float* Wqkv = (const float*)d_in[2];
  const float* bqkv = (const float*)d_in[3];
  const float* Wo   = (const float*)d_in[4];
  const float* bo   = (const float*)d_in[5];
  float* out = (float*)d_out;

  char* ws = (char*)d_ws;
  unsigned char*  Xf8   = (unsigned char*)ws;                        // 8.4 MB (region 16 MB)
  unsigned char*  Wtq8  = (unsigned char*)(ws + 16777216);           // 3.1 MB (region 6 MB)
  unsigned char*  Wto8  = (unsigned char*)(ws + 16777216 + 6291456); // 1.05 MB (region 2 MB)
  unsigned short* QKVb  = (unsigned short*)(ws + 16777216 + 6291456 + 2097152);
  unsigned char*  Attnb = (unsigned char*)ws;   // X dead after QKV GEMM; reuse (fp8)

  cvt_f32_fp8<<<dim3(8192), dim3(256), 0, stream>>>(X, Xf8, Mrows * Dn);
  transpose_cvt_fp8<<<dim3(96, 32), dim3(32, 8), 0, stream>>>(Wqkv, Wtq8, Dn, D3);
  transpose_cvt_fp8<<<dim3(32, 32), dim3(32, 8), 0, stream>>>(Wo, Wto8, Dn, Dn);

  gemm_fp8<true><<<dim3(64, 12), dim3(512), 0, stream>>>(Xf8, Wtq8, bqkv, (void*)QKVb, D3, Dn);
  attn_pair<<<dim3(64, 4), dim3(512), 0, stream>>>(QKVb, Attnb);
  gemm_fp8<false><<<dim3(64, 4), dim3(512), 0, stream>>>(Attnb, Wto8, bo, d_out, Dn, Dn);
  copy_len<<<dim3(1), dim3(64), 0, stream>>>(slen, out + (size_t)Mrows * Dn, Bn);
}